// Round 17
// baseline (817.466 us; speedup 1.0000x reference)
//
#include <hip/hip_runtime.h>

// SpikeLinear: out = LIF_scan( x @ W^T + bias ) over T=8 timesteps.
//
// Numerics (DO NOT CHANGE): must reproduce numpy/OpenBLAS sgemm bit-for-bit
// because the spike threshold (memb > 1.0) is discontinuous. OpenBLAS
// accumulates each C element as a strict sequential fp32 FMA chain over
// ascending k, blocked by kc=384: each panel accumulates from zero in
// registers, then C += panel (fp32 add) in ascending panel order, then fp32
// bias add and fp32 LIF scan. Verified absmax == 0.0 in rounds 3, 8-16.
//
// Perf lineage:
//  r13 (best, 800us / 381us/slice): 8x8 tile, reg-staged, stride-260 wsh
//    (2-way writes), prefetch regs, 2 barriers/step, BK=16.
//  r14 (launch bounds) null. r15 (8x16) null via occupancy collapse.
//  r16 (DMA W-staging) null: staging-VALU savings canceled by k-chunked
//    layout's bank conflicts (3.6e7). Wall decomposition: LDS-read pipe
//    ~338us/slice (4 b128/k/wave) + ~95us per-step fixed cost (24 steps).
//  r17 (this): r13 base with BK=32 -> 12 steps/panel: barrier count, vmcnt
//    drains, prefetch-issue overhead halve; LDS reads & FMA unchanged.
//    Prefetch = 10 float4 (40 VGPR live across FMA) -> (256,1) cap 512;
//    LDS 41KB -> 3 blocks/CU. Staging stays 2-way bank-free (68/260 == 4
//    mod 32 for (tid&3)*8 k-offsets).

typedef float v2f __attribute__((ext_vector_type(2)));

// acc = x.word0 * w + acc   (x broadcast from word0 of the pair)
#define PK_LO(a, x, wv)                                                       \
    asm("v_pk_fma_f32 %0, %1, %2, %0 op_sel:[0,0,0] op_sel_hi:[0,1,1]"        \
        : "+v"(a) : "v"(x), "v"(wv))
// acc = x.word1 * w + acc   (x broadcast from word1 of the pair)
#define PK_HI(a, x, wv)                                                       \
    asm("v_pk_fma_f32 %0, %1, %2, %0 op_sel:[1,0,0] op_sel_hi:[1,1,1]"        \
        : "+v"(a) : "v"(x), "v"(wv))

constexpr int TSTEPS = 8;
constexpr int BK     = 32;    // panel-kernel k-step (KC = 12*32; last 8*32)
constexpr int BKF    = 16;    // fallback-kernel k-step
constexpr int TILE_M = 64;    // 8 batches * 8 timesteps
constexpr int TILE_NP= 256;   // panel-kernel tile: 4 waves x 64 cols
constexpr int TILE_N = 128;   // fallback-kernel tile
constexpr int KC     = 384;   // OpenBLAS SGEMM_DEFAULT_Q on x86-64
constexpr int WS_PAD = 4;     // wsh row stride 260 == 4 mod 32 (bank spread)

// ---------------------------------------------------------------- phase 1 --
__global__ __launch_bounds__(256, 1)
void spike_panel_gemm(const float* __restrict__ x,
                      const float* __restrict__ w,
                      float* __restrict__ panels,   // ws: panels 0..np-2, NW cols
                      float* __restrict__ out,      // last panel, spike layout
                      int slice0, int NW,
                      int B, int IN, int OUT, int npanels)
{
    __shared__ float xs[BK][TILE_M + 4];
    __shared__ float wsh[BK][TILE_NP + WS_PAD];

    const int tid  = threadIdx.x;
    const int lane = tid & 63;
    const int wv   = tid >> 6;       // wave 0..3 -> col strip [64wv, 64wv+64)
    const int rg   = lane >> 3;      // row octet 0..7 -> batch within tile
    const int cg   = lane & 7;       // col quad index
    const int clo  = wv * 64 + cg * 4;      // cols clo..+3 and clo+32..+35

    const int m0 = blockIdx.y * TILE_M;
    const int n0 = slice0 + blockIdx.x * TILE_NP;
    const int p  = blockIdx.z;
    const int ks = p * KC;
    const int ke = (ks + KC < IN) ? (ks + KC) : IN;

    // acc[t][q]: q=0,1 -> cols {clo..+3}; q=2,3 -> cols {clo+32..+35}
    v2f acc[TSTEPS][4];
    #pragma unroll
    for (int t = 0; t < TSTEPS; ++t)
        #pragma unroll
        for (int q = 0; q < 4; ++q) acc[t][q] = (v2f){0.f, 0.f};

    // staging: thread -> (row sr, k-offset skx of 8); 2 float4 of x,
    // 8 float4 of w (4 rows x 8 k)
    const int sr  = tid >> 2;        // 0..63
    const int skx = (tid & 3) * 8;   // 0,8,16,24

    const float* xrow  = x + (size_t)(m0 + sr) * IN + skx;
    const float* wrow0 = w + (size_t)(n0 +       sr) * IN + skx;
    const float* wrow1 = w + (size_t)(n0 +  64 + sr) * IN + skx;
    const float* wrow2 = w + (size_t)(n0 + 128 + sr) * IN + skx;
    const float* wrow3 = w + (size_t)(n0 + 192 + sr) * IN + skx;

    const int nsteps = (ke - ks) / BK;   // 12 (full) or 8 (last panel)

    // prologue: load step 0 into prefetch registers
    float4 xva  = *(const float4*)(xrow  + ks);
    float4 xvb  = *(const float4*)(xrow  + ks + 4);
    float4 wva0 = *(const float4*)(wrow0 + ks);
    float4 wvb0 = *(const float4*)(wrow0 + ks + 4);
    float4 wva1 = *(const float4*)(wrow1 + ks);
    float4 wvb1 = *(const float4*)(wrow1 + ks + 4);
    float4 wva2 = *(const float4*)(wrow2 + ks);
    float4 wvb2 = *(const float4*)(wrow2 + ks + 4);
    float4 wva3 = *(const float4*)(wrow3 + ks);
    float4 wvb3 = *(const float4*)(wrow3 + ks + 4);

    for (int s = 0; s < nsteps; ++s) {
        __syncthreads();
        xs[skx+0][sr] = xva.x;  xs[skx+1][sr] = xva.y;
        xs[skx+2][sr] = xva.z;  xs[skx+3][sr] = xva.w;
        xs[skx+4][sr] = xvb.x;  xs[skx+5][sr] = xvb.y;
        xs[skx+6][sr] = xvb.z;  xs[skx+7][sr] = xvb.w;
        wsh[skx+0][sr]     = wva0.x; wsh[skx+1][sr]     = wva0.y;
        wsh[skx+2][sr]     = wva0.z; wsh[skx+3][sr]     = wva0.w;
        wsh[skx+4][sr]     = wvb0.x; wsh[skx+5][sr]     = wvb0.y;
        wsh[skx+6][sr]     = wvb0.z; wsh[skx+7][sr]     = wvb0.w;
        wsh[skx+0][sr+64]  = wva1.x; wsh[skx+1][sr+64]  = wva1.y;
        wsh[skx+2][sr+64]  = wva1.z; wsh[skx+3][sr+64]  = wva1.w;
        wsh[skx+4][sr+64]  = wvb1.x; wsh[skx+5][sr+64]  = wvb1.y;
        wsh[skx+6][sr+64]  = wvb1.z; wsh[skx+7][sr+64]  = wvb1.w;
        wsh[skx+0][sr+128] = wva2.x; wsh[skx+1][sr+128] = wva2.y;
        wsh[skx+2][sr+128] = wva2.z; wsh[skx+3][sr+128] = wva2.w;
        wsh[skx+4][sr+128] = wvb2.x; wsh[skx+5][sr+128] = wvb2.y;
        wsh[skx+6][sr+128] = wvb2.z; wsh[skx+7][sr+128] = wvb2.w;
        wsh[skx+0][sr+192] = wva3.x; wsh[skx+1][sr+192] = wva3.y;
        wsh[skx+2][sr+192] = wva3.z; wsh[skx+3][sr+192] = wva3.w;
        wsh[skx+4][sr+192] = wvb3.x; wsh[skx+5][sr+192] = wvb3.y;
        wsh[skx+6][sr+192] = wvb3.z; wsh[skx+7][sr+192] = wvb3.w;
        __syncthreads();

        // prefetch step s+1: latency hides under the 32-k FMA block below
        if (s + 1 < nsteps) {
            const int ko = ks + (s + 1) * BK;
            xva  = *(const float4*)(xrow  + ko);
            xvb  = *(const float4*)(xrow  + ko + 4);
            wva0 = *(const float4*)(wrow0 + ko);
            wvb0 = *(const float4*)(wrow0 + ko + 4);
            wva1 = *(const float4*)(wrow1 + ko);
            wvb1 = *(const float4*)(wrow1 + ko + 4);
            wva2 = *(const float4*)(wrow2 + ko);
            wvb2 = *(const float4*)(wrow2 + ko + 4);
            wva3 = *(const float4*)(wrow3 + ko);
            wvb3 = *(const float4*)(wrow3 + ko + 4);
        }

        #pragma unroll
        for (int k = 0; k < BK; ++k) {
            // xp[tp] = {x[2tp], x[2tp+1]} for this thread's batch row
            v2f xp[4], wva[4];
            *(float4*)&xp[0]  = *(const float4*)&xs[k][rg*8];
            *(float4*)&xp[2]  = *(const float4*)&xs[k][rg*8 + 4];
            *(float4*)&wva[0] = *(const float4*)&wsh[k][clo];
            *(float4*)&wva[2] = *(const float4*)&wsh[k][clo + 32];
            #pragma unroll
            for (int tp = 0; tp < 4; ++tp) {
                #pragma unroll
                for (int q = 0; q < 4; ++q) {
                    PK_LO(acc[2*tp  ][q], xp[tp], wva[q]);
                    PK_HI(acc[2*tp+1][q], xp[tp], wva[q]);
                }
            }
        }
    }

    const int bg = blockIdx.y * 8 + rg;            // global batch index
    const int cs = blockIdx.x * TILE_NP + clo;     // col within slice
    if (p < npanels - 1) {
        // panels 0..np-2: m-major rows (b*8 + t), NW-wide, slot p in ws
        float* pb = panels + ((size_t)p * B * TSTEPS) * NW;
        #pragma unroll
        for (int t = 0; t < TSTEPS; ++t) {
            const int m = bg * TSTEPS + t;
            float4 lo, hi;
            *(v2f*)&lo.x = acc[t][0]; *(v2f*)&lo.z = acc[t][1];
            *(v2f*)&hi.x = acc[t][2]; *(v2f*)&hi.z = acc[t][3];
            *(float4*)(pb + (size_t)m * NW + cs)      = lo;
            *(float4*)(pb + (size_t)m * NW + cs + 32) = hi;
        }
    } else {
        // last panel -> out with SPIKE row mapping (t*B + b): phase 2's
        // reader thread == writer thread (no cross-thread hazard).
        const int o0 = n0 + clo;
        #pragma unroll
        for (int t = 0; t < TSTEPS; ++t) {
            float4 lo, hi;
            *(v2f*)&lo.x = acc[t][0]; *(v2f*)&lo.z = acc[t][1];
            *(v2f*)&hi.x = acc[t][2]; *(v2f*)&hi.z = acc[t][3];
            float* op = out + ((size_t)t * B + bg) * OUT + o0;
            *(float4*)op        = lo;
            *(float4*)(op + 32) = hi;
        }
    }
}

// ---------------------------------------------------------------- phase 2 --
__global__ __launch_bounds__(256)
void spike_fold_scan(const float* __restrict__ panels,
                     const float* __restrict__ bias,
                     float* __restrict__ out,
                     int slice0, int NW,
                     int B, int OUT, int npanels)
{
    const int b = blockIdx.y;
    const size_t psz = (size_t)B * TSTEPS * NW;
    const int nc4 = NW / 4;

    for (int c4 = blockIdx.x * 256 + threadIdx.x; c4 < nc4;
         c4 += gridDim.x * 256) {
        const int cs   = c4 * 4;          // col within slice
        const int gcol = slice0 + cs;     // global col

        // v = panel0; v += panel1 ... += panel(np-2)  (exact BLAS order)
        float4 v[TSTEPS];
        #pragma unroll
        for (int t = 0; t < TSTEPS; ++t)
            v[t] = *(const float4*)(panels + (size_t)(b*TSTEPS + t) * NW + cs);
        for (int p = 1; p < npanels - 1; ++p) {
            const float* pb = panels + (size_t)p * psz;
            #pragma unroll
            for (int t = 0; t < TSTEPS; ++t) {
                const float4 u = *(const float4*)(pb + (size_t)(b*TSTEPS + t) * NW + cs);
                v[t].x += u.x; v[t].y += u.y; v[t].z += u.z; v[t].w += u.w;
            }
        }
        // last panel from out (spike layout, owned by this thread)
        #pragma unroll
        for (int t = 0; t < TSTEPS; ++t) {
            const float4 u = *(const float4*)(out + ((size_t)t * B + b) * OUT + gcol);
            v[t].x += u.x; v[t].y += u.y; v[t].z += u.z; v[t].w += u.w;
        }

        const float4 bb = *(const float4*)(bias + gcol);
        float memb[4] = {0.f, 0.f, 0.f, 0.f};
        #pragma unroll
        for (int t = 0; t < TSTEPS; ++t) {
            float pre[4] = {v[t].x + bb.x, v[t].y + bb.y,
                            v[t].z + bb.z, v[t].w + bb.w};
            float4 sp;
            float* spp = (float*)&sp;
            #pragma unroll
            for (int c = 0; c < 4; ++c) {
                memb[c] += pre[c];                       // VTHR = 1.0 (exact)
                float s = (memb[c] > 1.0f) ? 1.0f : 0.0f;
                memb[c] *= (1.0f - s);                   // reset to zero
                spp[c] = s;
            }
            *(float4*)(out + ((size_t)t * B + b) * OUT + gcol) = sp;
        }
    }
}

// ------------------------------------------------- fallback: r3 (verified) --
__global__ __launch_bounds__(256, 4)
void spike_linear_f32seq(const float* __restrict__ x,
                         const float* __restrict__ w,
                         const float* __restrict__ bias,
                         float* __restrict__ out,
                         int B, int IN, int OUT)
{
    __shared__ float xs[BKF][TILE_M + 4];
    __shared__ float ws[BKF][TILE_N + 4];

    const int tid = threadIdx.x;
    const int tx  = tid & 31;
    const int ty  = tid >> 5;

    const int m0 = blockIdx.y * TILE_M;
    const int n0 = blockIdx.x * TILE_N;

    float acc_tot[TSTEPS][4];
    float acc_blk[TSTEPS][4];
    #pragma unroll
    for (int t = 0; t < TSTEPS; ++t)
        #pragma unroll
        for (int c = 0; c < 4; ++c) { acc_tot[t][c] = 0.f; acc_blk[t][c] = 0.f; }

    const int sr = tid >> 2;
    const int sk = (tid & 3) * 4;

    const float* xrow  = x + (size_t)(m0 + sr) * IN + sk;
    const float* wrow0 = w + (size_t)(n0 + sr) * IN + sk;
    const float* wrow1 = w + (size_t)(n0 + 64 + sr) * IN + sk;

    for (int kk = 0; kk < IN; kk += BKF) {
        if (kk > 0 && (kk % KC) == 0) {
            #pragma unroll
            for (int t = 0; t < TSTEPS; ++t)
                #pragma unroll
                for (int c = 0; c < 4; ++c) {
                    acc_tot[t][c] += acc_blk[t][c];
                    acc_blk[t][c] = 0.f;
                }
        }
        const float4 xv  = *(const float4*)(xrow  + kk);
        const float4 wv0 = *(const float4*)(wrow0 + kk);
        const float4 wv1 = *(const float4*)(wrow1 + kk);
        __syncthreads();
        xs[sk+0][sr] = xv.x;  xs[sk+1][sr] = xv.y;
        xs[sk+2][sr] = xv.z;  xs[sk+3][sr] = xv.w;
        ws[sk+0][sr]    = wv0.x; ws[sk+1][sr]    = wv0.y;
        ws[sk+2][sr]    = wv0.z; ws[sk+3][sr]    = wv0.w;
        ws[sk+0][sr+64] = wv1.x; ws[sk+1][sr+64] = wv1.y;
        ws[sk+2][sr+64] = wv1.z; ws[sk+3][sr+64] = wv1.w;
        __syncthreads();

        #pragma unroll
        for (int k = 0; k < BKF; ++k) {
            float xr[TSTEPS];
            *(float4*)&xr[0] = *(const float4*)&xs[k][ty*8];
            *(float4*)&xr[4] = *(const float4*)&xs[k][ty*8 + 4];
            float wr[4];
            *(float4*)&wr[0] = *(const float4*)&ws[k][tx*4];
            #pragma unroll
            for (int t = 0; t < TSTEPS; ++t)
                #pragma unroll
                for (int c = 0; c < 4; ++c)
                    acc_blk[t][c] = fmaf(xr[t], wr[c], acc_blk[t][c]);
        }
    }
    #pragma unroll
    for (int t = 0; t < TSTEPS; ++t)
        #pragma unroll
        for (int c = 0; c < 4; ++c)
            acc_tot[t][c] += acc_blk[t][c];

    const int bg = blockIdx.y * 8 + ty;
    const int o0 = n0 + tx * 4;
    const float4 bv = *(const float4*)(bias + o0);
    const float bb[4] = {bv.x, bv.y, bv.z, bv.w};
    float memb[4] = {0.f, 0.f, 0.f, 0.f};
    #pragma unroll
    for (int t = 0; t < TSTEPS; ++t) {
        float4 sp;
        float* spp = (float*)&sp;
        #pragma unroll
        for (int c = 0; c < 4; ++c) {
            float pre = acc_tot[t][c] + bb[c];
            memb[c] += pre;
            float s = (memb[c] > 1.0f) ? 1.0f : 0.0f;
            memb[c] *= (1.0f - s);
            spp[c] = s;
        }
        *(float4*)(out + ((size_t)t * B + bg) * OUT + o0) = sp;
    }
}

extern "C" void kernel_launch(void* const* d_in, const int* in_sizes, int n_in,
                              void* d_out, int out_size, void* d_ws, size_t ws_size,
                              hipStream_t stream)
{
    const float* x    = (const float*)d_in[0];
    const float* w    = (const float*)d_in[1];
    const float* bias = (const float*)d_in[2];
    float* out = (float*)d_out;

    const int OUT = in_sizes[2];            // 4096
    const int IN  = in_sizes[1] / OUT;      // 4096
    const int BT  = in_sizes[0] / IN;       // 2048
    const int B   = BT / TSTEPS;            // 256

    const int npanels = (IN + KC - 1) / KC; // 11

    // pick the widest column slice whose panel storage fits ws
    int NW = 0;
    for (int cand = 4096; cand >= 256; cand >>= 1) {
        if ((OUT % cand) == 0 &&
            (size_t)(npanels - 1) * BT * cand * sizeof(float) <= ws_size) {
            NW = cand;
            break;
        }
    }

    if (NW >= 256 && npanels >= 2) {
        float* panels = (float*)d_ws;
        const int nslices = OUT / NW;
        for (int s = 0; s < nslices; ++s) {
            const int slice0 = s * NW;
            dim3 g1(NW / TILE_NP, BT / TILE_M, npanels);
            spike_panel_gemm<<<g1, 256, 0, stream>>>(x, w, panels, out,
                                                     slice0, NW, B, IN, OUT,
                                                     npanels);
            int gx = NW / 1024; if (gx < 1) gx = 1;
            dim3 g2(gx, B);
            spike_fold_scan<<<g2, 256, 0, stream>>>(panels, bias, out,
                                                    slice0, NW, B, OUT,
                                                    npanels);
        }
    } else {
        dim3 grid(OUT / TILE_N, BT / TILE_M);          // (32, 32)
        spike_linear_f32seq<<<grid, 256, 0, stream>>>(x, w, bias, out, B, IN, OUT);
    }
}

// Round 18
// 800.833 us; speedup vs baseline: 1.0208x; 1.0208x over previous
//
#include <hip/hip_runtime.h>

// SpikeLinear: out = LIF_scan( x @ W^T + bias ) over T=8 timesteps.
//
// Numerics (DO NOT CHANGE): must reproduce numpy/OpenBLAS sgemm bit-for-bit
// because the spike threshold (memb > 1.0) is discontinuous. OpenBLAS
// accumulates each C element as a strict sequential fp32 FMA chain over
// ascending k, blocked by kc=384: each panel accumulates from zero in
// registers, then C += panel (fp32 add) in ascending panel order, then fp32
// bias add and fp32 LIF scan. Verified absmax == 0.0 in rounds 3, 8-17.
//
// FINAL STRUCTURE (= r13, the measured best: 800us total, 381us/slice):
//  - K-split at OpenBLAS kc=384 panel boundaries (the only legal split):
//    11 independent panel GEMMs -> ws / out, then fold+bias+LIF scan.
//  - 8x8 thread tile via v_pk_fma_f32 (2 bit-identical IEEE FMAs/inst).
//  - k-major LDS, wsh stride 260 (==4 mod 32: staging writes 2-way = free),
//    conflict-free b128 reads (cols cg*4 / +32), reg prefetch, (256,2).
//  Roofline: LDS-read pipe. 4 ds_read_b128/k/wave x 12cyc (m134) = 338us
//  of the 381us slice (89%); pk-FMA floor 218us. All orthogonal levers
//  isolated-null: launch-bounds (r14), 8x16 tile (r15, occupancy cliff),
//  global_load_lds DMA (r16, layout conflicts), BK=32 (r17). Structures
//  with fewer LDS bytes/MAC exceed the register file at useful occupancy.
//  MFMA is forbidden by the bit-exactness requirement.

typedef float v2f __attribute__((ext_vector_type(2)));

// acc = x.word0 * w + acc   (x broadcast from word0 of the pair)
#define PK_LO(a, x, wv)                                                       \
    asm("v_pk_fma_f32 %0, %1, %2, %0 op_sel:[0,0,0] op_sel_hi:[0,1,1]"        \
        : "+v"(a) : "v"(x), "v"(wv))
// acc = x.word1 * w + acc   (x broadcast from word1 of the pair)
#define PK_HI(a, x, wv)                                                       \
    asm("v_pk_fma_f32 %0, %1, %2, %0 op_sel:[1,0,0] op_sel_hi:[1,1,1]"        \
        : "+v"(a) : "v"(x), "v"(wv))

constexpr int TSTEPS = 8;
constexpr int BK     = 16;
constexpr int TILE_M = 64;    // 8 batches * 8 timesteps
constexpr int TILE_NP= 256;   // panel-kernel tile: 4 waves x 64 cols
constexpr int TILE_N = 128;   // fallback-kernel tile
constexpr int KC     = 384;   // OpenBLAS SGEMM_DEFAULT_Q on x86-64
constexpr int WS_PAD = 4;     // wsh row stride 260 == 4 mod 32 (bank spread)

// ---------------------------------------------------------------- phase 1 --
__global__ __launch_bounds__(256, 2)
void spike_panel_gemm(const float* __restrict__ x,
                      const float* __restrict__ w,
                      float* __restrict__ panels,   // ws: panels 0..np-2, NW cols
                      float* __restrict__ out,      // last panel, spike layout
                      int slice0, int NW,
                      int B, int IN, int OUT, int npanels)
{
    __shared__ float xs[BK][TILE_M + 4];
    __shared__ float wsh[BK][TILE_NP + WS_PAD];

    const int tid  = threadIdx.x;
    const int lane = tid & 63;
    const int wv   = tid >> 6;       // wave 0..3 -> col strip [64wv, 64wv+64)
    const int rg   = lane >> 3;      // row octet 0..7 -> batch within tile
    const int cg   = lane & 7;       // col quad index
    const int clo  = wv * 64 + cg * 4;      // cols clo..+3 and clo+32..+35

    const int m0 = blockIdx.y * TILE_M;
    const int n0 = slice0 + blockIdx.x * TILE_NP;
    const int p  = blockIdx.z;
    const int ks = p * KC;
    const int ke = (ks + KC < IN) ? (ks + KC) : IN;

    // acc[t][q]: q=0,1 -> cols {clo..+3}; q=2,3 -> cols {clo+32..+35}
    v2f acc[TSTEPS][4];
    #pragma unroll
    for (int t = 0; t < TSTEPS; ++t)
        #pragma unroll
        for (int q = 0; q < 4; ++q) acc[t][q] = (v2f){0.f, 0.f};

    const int sr = tid >> 2;         // 0..63
    const int sk = (tid & 3) * 4;    // 0,4,8,12

    const float* xrow  = x + (size_t)(m0 + sr) * IN + sk;
    const float* wrow0 = w + (size_t)(n0 +       sr) * IN + sk;
    const float* wrow1 = w + (size_t)(n0 +  64 + sr) * IN + sk;
    const float* wrow2 = w + (size_t)(n0 + 128 + sr) * IN + sk;
    const float* wrow3 = w + (size_t)(n0 + 192 + sr) * IN + sk;

    const int nsteps = (ke - ks) / BK;

    // prologue: load step 0 into prefetch registers
    float4 xv  = *(const float4*)(xrow  + ks);
    float4 wv0 = *(const float4*)(wrow0 + ks);
    float4 wv1 = *(const float4*)(wrow1 + ks);
    float4 wv2 = *(const float4*)(wrow2 + ks);
    float4 wv3 = *(const float4*)(wrow3 + ks);

    for (int s = 0; s < nsteps; ++s) {
        __syncthreads();
        xs[sk+0][sr] = xv.x;  xs[sk+1][sr] = xv.y;
        xs[sk+2][sr] = xv.z;  xs[sk+3][sr] = xv.w;
        wsh[sk+0][sr]     = wv0.x; wsh[sk+1][sr]     = wv0.y;
        wsh[sk+2][sr]     = wv0.z; wsh[sk+3][sr]     = wv0.w;
        wsh[sk+0][sr+64]  = wv1.x; wsh[sk+1][sr+64]  = wv1.y;
        wsh[sk+2][sr+64]  = wv1.z; wsh[sk+3][sr+64]  = wv1.w;
        wsh[sk+0][sr+128] = wv2.x; wsh[sk+1][sr+128] = wv2.y;
        wsh[sk+2][sr+128] = wv2.z; wsh[sk+3][sr+128] = wv2.w;
        wsh[sk+0][sr+192] = wv3.x; wsh[sk+1][sr+192] = wv3.y;
        wsh[sk+2][sr+192] = wv3.z; wsh[sk+3][sr+192] = wv3.w;
        __syncthreads();

        // prefetch step s+1: latency hides under the 16-k FMA block below
        if (s + 1 < nsteps) {
            const int ko = ks + (s + 1) * BK;
            xv  = *(const float4*)(xrow  + ko);
            wv0 = *(const float4*)(wrow0 + ko);
            wv1 = *(const float4*)(wrow1 + ko);
            wv2 = *(const float4*)(wrow2 + ko);
            wv3 = *(const float4*)(wrow3 + ko);
        }

        #pragma unroll
        for (int k = 0; k < BK; ++k) {
            // xp[tp] = {x[2tp], x[2tp+1]} for this thread's batch row
            v2f xp[4], wva[4];
            *(float4*)&xp[0]  = *(const float4*)&xs[k][rg*8];
            *(float4*)&xp[2]  = *(const float4*)&xs[k][rg*8 + 4];
            *(float4*)&wva[0] = *(const float4*)&wsh[k][clo];
            *(float4*)&wva[2] = *(const float4*)&wsh[k][clo + 32];
            #pragma unroll
            for (int tp = 0; tp < 4; ++tp) {
                #pragma unroll
                for (int q = 0; q < 4; ++q) {
                    PK_LO(acc[2*tp  ][q], xp[tp], wva[q]);
                    PK_HI(acc[2*tp+1][q], xp[tp], wva[q]);
                }
            }
        }
    }

    const int bg = blockIdx.y * 8 + rg;            // global batch index
    const int cs = blockIdx.x * TILE_NP + clo;     // col within slice
    if (p < npanels - 1) {
        // panels 0..np-2: m-major rows (b*8 + t), NW-wide, slot p in ws
        float* pb = panels + ((size_t)p * B * TSTEPS) * NW;
        #pragma unroll
        for (int t = 0; t < TSTEPS; ++t) {
            const int m = bg * TSTEPS + t;
            float4 lo, hi;
            *(v2f*)&lo.x = acc[t][0]; *(v2f*)&lo.z = acc[t][1];
            *(v2f*)&hi.x = acc[t][2]; *(v2f*)&hi.z = acc[t][3];
            *(float4*)(pb + (size_t)m * NW + cs)      = lo;
            *(float4*)(pb + (size_t)m * NW + cs + 32) = hi;
        }
    } else {
        // last panel -> out with SPIKE row mapping (t*B + b): phase 2's
        // reader thread == writer thread (no cross-thread hazard).
        const int o0 = n0 + clo;
        #pragma unroll
        for (int t = 0; t < TSTEPS; ++t) {
            float4 lo, hi;
            *(v2f*)&lo.x = acc[t][0]; *(v2f*)&lo.z = acc[t][1];
            *(v2f*)&hi.x = acc[t][2]; *(v2f*)&hi.z = acc[t][3];
            float* op = out + ((size_t)t * B + bg) * OUT + o0;
            *(float4*)op        = lo;
            *(float4*)(op + 32) = hi;
        }
    }
}

// ---------------------------------------------------------------- phase 2 --
__global__ __launch_bounds__(256)
void spike_fold_scan(const float* __restrict__ panels,
                     const float* __restrict__ bias,
                     float* __restrict__ out,
                     int slice0, int NW,
                     int B, int OUT, int npanels)
{
    const int b = blockIdx.y;
    const size_t psz = (size_t)B * TSTEPS * NW;
    const int nc4 = NW / 4;

    for (int c4 = blockIdx.x * 256 + threadIdx.x; c4 < nc4;
         c4 += gridDim.x * 256) {
        const int cs   = c4 * 4;          // col within slice
        const int gcol = slice0 + cs;     // global col

        // v = panel0; v += panel1 ... += panel(np-2)  (exact BLAS order)
        float4 v[TSTEPS];
        #pragma unroll
        for (int t = 0; t < TSTEPS; ++t)
            v[t] = *(const float4*)(panels + (size_t)(b*TSTEPS + t) * NW + cs);
        for (int p = 1; p < npanels - 1; ++p) {
            const float* pb = panels + (size_t)p * psz;
            #pragma unroll
            for (int t = 0; t < TSTEPS; ++t) {
                const float4 u = *(const float4*)(pb + (size_t)(b*TSTEPS + t) * NW + cs);
                v[t].x += u.x; v[t].y += u.y; v[t].z += u.z; v[t].w += u.w;
            }
        }
        // last panel from out (spike layout, owned by this thread)
        #pragma unroll
        for (int t = 0; t < TSTEPS; ++t) {
            const float4 u = *(const float4*)(out + ((size_t)t * B + b) * OUT + gcol);
            v[t].x += u.x; v[t].y += u.y; v[t].z += u.z; v[t].w += u.w;
        }

        const float4 bb = *(const float4*)(bias + gcol);
        float memb[4] = {0.f, 0.f, 0.f, 0.f};
        #pragma unroll
        for (int t = 0; t < TSTEPS; ++t) {
            float pre[4] = {v[t].x + bb.x, v[t].y + bb.y,
                            v[t].z + bb.z, v[t].w + bb.w};
            float4 sp;
            float* spp = (float*)&sp;
            #pragma unroll
            for (int c = 0; c < 4; ++c) {
                memb[c] += pre[c];                       // VTHR = 1.0 (exact)
                float s = (memb[c] > 1.0f) ? 1.0f : 0.0f;
                memb[c] *= (1.0f - s);                   // reset to zero
                spp[c] = s;
            }
            *(float4*)(out + ((size_t)t * B + b) * OUT + gcol) = sp;
        }
    }
}

// ------------------------------------------------- fallback: r3 (verified) --
__global__ __launch_bounds__(256, 4)
void spike_linear_f32seq(const float* __restrict__ x,
                         const float* __restrict__ w,
                         const float* __restrict__ bias,
                         float* __restrict__ out,
                         int B, int IN, int OUT)
{
    __shared__ float xs[BK][TILE_M + 4];
    __shared__ float ws[BK][TILE_N + 4];

    const int tid = threadIdx.x;
    const int tx  = tid & 31;
    const int ty  = tid >> 5;

    const int m0 = blockIdx.y * TILE_M;
    const int n0 = blockIdx.x * TILE_N;

    float acc_tot[TSTEPS][4];
    float acc_blk[TSTEPS][4];
    #pragma unroll
    for (int t = 0; t < TSTEPS; ++t)
        #pragma unroll
        for (int c = 0; c < 4; ++c) { acc_tot[t][c] = 0.f; acc_blk[t][c] = 0.f; }

    const int sr = tid >> 2;
    const int sk = (tid & 3) * 4;

    const float* xrow  = x + (size_t)(m0 + sr) * IN + sk;
    const float* wrow0 = w + (size_t)(n0 + sr) * IN + sk;
    const float* wrow1 = w + (size_t)(n0 + 64 + sr) * IN + sk;

    for (int kk = 0; kk < IN; kk += BK) {
        if (kk > 0 && (kk % KC) == 0) {
            #pragma unroll
            for (int t = 0; t < TSTEPS; ++t)
                #pragma unroll
                for (int c = 0; c < 4; ++c) {
                    acc_tot[t][c] += acc_blk[t][c];
                    acc_blk[t][c] = 0.f;
                }
        }
        const float4 xv  = *(const float4*)(xrow  + kk);
        const float4 wv0 = *(const float4*)(wrow0 + kk);
        const float4 wv1 = *(const float4*)(wrow1 + kk);
        __syncthreads();
        xs[sk+0][sr] = xv.x;  xs[sk+1][sr] = xv.y;
        xs[sk+2][sr] = xv.z;  xs[sk+3][sr] = xv.w;
        ws[sk+0][sr]    = wv0.x; ws[sk+1][sr]    = wv0.y;
        ws[sk+2][sr]    = wv0.z; ws[sk+3][sr]    = wv0.w;
        ws[sk+0][sr+64] = wv1.x; ws[sk+1][sr+64] = wv1.y;
        ws[sk+2][sr+64] = wv1.z; ws[sk+3][sr+64] = wv1.w;
        __syncthreads();

        #pragma unroll
        for (int k = 0; k < BK; ++k) {
            float xr[TSTEPS];
            *(float4*)&xr[0] = *(const float4*)&xs[k][ty*8];
            *(float4*)&xr[4] = *(const float4*)&xs[k][ty*8 + 4];
            float wr[4];
            *(float4*)&wr[0] = *(const float4*)&ws[k][tx*4];
            #pragma unroll
            for (int t = 0; t < TSTEPS; ++t)
                #pragma unroll
                for (int c = 0; c < 4; ++c)
                    acc_blk[t][c] = fmaf(xr[t], wr[c], acc_blk[t][c]);
        }
    }
    #pragma unroll
    for (int t = 0; t < TSTEPS; ++t)
        #pragma unroll
        for (int c = 0; c < 4; ++c)
            acc_tot[t][c] += acc_blk[t][c];

    const int bg = blockIdx.y * 8 + ty;
    const int o0 = n0 + tx * 4;
    const float4 bv = *(const float4*)(bias + o0);
    const float bb[4] = {bv.x, bv.y, bv.z, bv.w};
    float memb[4] = {0.f, 0.f, 0.f, 0.f};
    #pragma unroll
    for (int t = 0; t < TSTEPS; ++t) {
        float4 sp;
        float* spp = (float*)&sp;
        #pragma unroll
        for (int c = 0; c < 4; ++c) {
            float pre = acc_tot[t][c] + bb[c];
            memb[c] += pre;
            float s = (memb[c] > 1.0f) ? 1.0f : 0.0f;
            memb[c] *= (1.0f - s);
            spp[c] = s;
        }
        *(float4*)(out + ((size_t)t * B + bg) * OUT + o0) = sp;
    }
}

extern "C" void kernel_launch(void* const* d_in, const int* in_sizes, int n_in,
                              void* d_out, int out_size, void* d_ws, size_t ws_size,
                              hipStream_t stream)
{
    const float* x    = (const float*)d_in[0];
    const float* w    = (const float*)d_in[1];
    const float* bias = (const float*)d_in[2];
    float* out = (float*)d_out;

    const int OUT = in_sizes[2];            // 4096
    const int IN  = in_sizes[1] / OUT;      // 4096
    const int BT  = in_sizes[0] / IN;       // 2048
    const int B   = BT / TSTEPS;            // 256

    const int npanels = (IN + KC - 1) / KC; // 11

    // pick the widest column slice whose panel storage fits ws
    int NW = 0;
    for (int cand = 4096; cand >= 256; cand >>= 1) {
        if ((OUT % cand) == 0 &&
            (size_t)(npanels - 1) * BT * cand * sizeof(float) <= ws_size) {
            NW = cand;
            break;
        }
    }

    if (NW >= 256 && npanels >= 2) {
        float* panels = (float*)d_ws;
        const int nslices = OUT / NW;
        for (int s = 0; s < nslices; ++s) {
            const int slice0 = s * NW;
            dim3 g1(NW / TILE_NP, BT / TILE_M, npanels);
            spike_panel_gemm<<<g1, 256, 0, stream>>>(x, w, panels, out,
                                                     slice0, NW, B, IN, OUT,
                                                     npanels);
            int gx = NW / 1024; if (gx < 1) gx = 1;
            dim3 g2(gx, B);
            spike_fold_scan<<<g2, 256, 0, stream>>>(panels, bias, out,
                                                    slice0, NW, B, OUT,
                                                    npanels);
        }
    } else {
        dim3 grid(OUT / TILE_N, BT / TILE_M);          // (32, 32)
        spike_linear_f32seq<<<grid, 256, 0, stream>>>(x, w, bias, out, B, IN, OUT);
    }
}